// Round 5
// baseline (204.777 us; speedup 1.0000x reference)
//
#include <hip/hip_runtime.h>
#include <math.h>

// Problem constants (fixed by the reference)
#define N_TOT 200000
#define D_    32
#define MK    1024          // M*K = 64*16
#define EPS_ZERO 1e-5f
#define EPS_DIV  1e-29f

// Tiling
#define BN   64             // n rows per block
#define BMK  256            // (m,k) columns per block
#define NB_N (N_TOT / BN)   // 3125
#define NB_MK (MK / BMK)    // 4

typedef __attribute__((ext_vector_type(8))) short short8;
typedef __attribute__((ext_vector_type(4))) float f32x4;

__device__ __forceinline__ unsigned short f2bf(float x) {
    unsigned int u = __float_as_uint(x);
    u += 0x7FFFu + ((u >> 16) & 1u);          // round-to-nearest-even
    return (unsigned short)(u >> 16);
}
__device__ __forceinline__ float bf2f(unsigned short h) {
    return __uint_as_float(((unsigned int)h) << 16);
}

// ---------------------------------------------------------------------------
// Prep: softmax(alpha) folded with affine epilogue, split into bf16 hi/lo.
//   W[mk][d] = softmax(alpha[mk])[d] / (pos-neg+eps)   -> Whi + Wlo (bf16)
//   ot[mk]   = { (-th-neg)/(pos-neg+eps),  EPS_ZERO/(pos-neg+eps) }
// Then B = clip( |acc| < thr ? off : acc + off, 0, 1 ),  acc = T·W
// ---------------------------------------------------------------------------
__global__ __launch_bounds__(256) void prep_kernel(
    const float* __restrict__ alpha, const float* __restrict__ th,
    const float* __restrict__ amb,
    unsigned short* __restrict__ Whi, unsigned short* __restrict__ Wlo,
    float* __restrict__ ot)
{
    int mk = blockIdx.x * 256 + threadIdx.x;
    if (mk >= MK) return;
    float v[D_];
    float mx = -1e30f;
#pragma unroll
    for (int d = 0; d < D_; ++d) { v[d] = alpha[mk * D_ + d]; mx = fmaxf(mx, v[d]); }
    float sum = 0.f;
#pragma unroll
    for (int d = 0; d < D_; ++d) { v[d] = expf(v[d] - mx); sum += v[d]; }
    float pos = amb[mk * 2 + 0];
    float neg = amb[mk * 2 + 1];
    float s  = 1.0f / (pos - neg + EPS_DIV);
    float si = s / sum;
#pragma unroll
    for (int d = 0; d < D_; ++d) {
        float w = v[d] * si;
        unsigned short h = f2bf(w);
        Whi[mk * D_ + d] = h;
        Wlo[mk * D_ + d] = f2bf(w - bf2f(h));
    }
    ot[2 * mk + 0] = (0.0f - th[mk] - neg) * s;
    ot[2 * mk + 1] = EPS_ZERO * s;
}

// ---------------------------------------------------------------------------
// Main: out[n][mk] = clip(epilogue(T[n]·W[mk]), 0, 1) via bf16 MFMA,
// 3-MFMA hi/lo split for fp32-level accuracy.
// 256 threads = 4 waves; block tile 64n x 256mk; each wave owns 16 n-rows
// and loops 16 mk-tiles of 16 cols (K=32 in a single mfma_16x16x32).
// ---------------------------------------------------------------------------
__global__ __launch_bounds__(256) void fern_mfma(
    const float* __restrict__ T,
    const unsigned short* __restrict__ Whi, const unsigned short* __restrict__ Wlo,
    const float* __restrict__ ot, float* __restrict__ out)
{
    // Row stride 40 shorts = 80 B: bank stride 20 -> conflict-balanced b128 reads
    __shared__ __align__(16) short Thi_l[BN][40];    // 5120 B
    __shared__ __align__(16) short Tlo_l[BN][40];    // 5120 B
    __shared__ __align__(16) short Whi_l[BMK][40];   // 20480 B
    __shared__ __align__(16) short Wlo_l[BMK][40];   // 20480 B
    __shared__ float2 ot_l[BMK];                     // 2048 B  (total 53.2 KB -> 3 blk/CU)

    const int tid = threadIdx.x;
    const int bx  = blockIdx.x;
    const int nb  = bx % NB_N;          // n fastest: consecutive blocks share W tile
    const int mkq = bx / NB_N;
    const int n0  = nb * BN;
    const int mk0 = mkq * BMK;

    // ---- stage T (64 x 32 f32) -> hi/lo bf16, transposed-free [n][k] layout
    {
        int row = tid >> 2;
        int d0  = (tid & 3) * 8;
        const float* src = T + (long)(n0 + row) * D_ + d0;
        float4 v0 = *(const float4*)src;
        float4 v1 = *(const float4*)(src + 4);
        float xs[8] = { v0.x, v0.y, v0.z, v0.w, v1.x, v1.y, v1.z, v1.w };
        short8 vh, vl;
#pragma unroll
        for (int j = 0; j < 8; ++j) {
            unsigned short h = f2bf(xs[j]);
            vh[j] = (short)h;
            vl[j] = (short)f2bf(xs[j] - bf2f(h));
        }
        *(short8*)&Thi_l[row][d0] = vh;
        *(short8*)&Tlo_l[row][d0] = vl;
    }
    // ---- stage W (256 x 32 bf16, hi+lo): 16B chunks, 4 per thread each
#pragma unroll
    for (int i = 0; i < 4; ++i) {
        int f   = tid + i * 256;
        int col = f >> 2;
        int k0  = (f & 3) * 8;
        *(short8*)&Whi_l[col][k0] = *(const short8*)(Whi + (long)(mk0 + col) * D_ + k0);
        *(short8*)&Wlo_l[col][k0] = *(const short8*)(Wlo + (long)(mk0 + col) * D_ + k0);
    }
    ot_l[tid] = *(const float2*)(ot + 2 * (mk0 + tid));
    __syncthreads();

    const int lane = tid & 63;
    const int wid  = tid >> 6;          // wave owns rows [wid*16, wid*16+16)
    const int lc   = lane & 15;         // fragment row (A) / col (B/C)
    const int lk   = lane >> 4;         // k-group (8 consecutive k per lane)

    short8 ahi = *(const short8*)&Thi_l[wid * 16 + lc][lk * 8];
    short8 alo = *(const short8*)&Tlo_l[wid * 16 + lc][lk * 8];

    // C/D layout: col = lane&15, row = (lane>>4)*4 + j   [measured m89/m91]
    long rowbase = ((long)(n0 + wid * 16 + lk * 4)) * MK + mk0 + lc;

#pragma unroll 4
    for (int t = 0; t < 16; ++t) {
        short8 bhi = *(const short8*)&Whi_l[t * 16 + lc][lk * 8];
        short8 blo = *(const short8*)&Wlo_l[t * 16 + lc][lk * 8];
        f32x4 acc = { 0.f, 0.f, 0.f, 0.f };
        acc = __builtin_amdgcn_mfma_f32_16x16x32_bf16(ahi, bhi, acc, 0, 0, 0);
        acc = __builtin_amdgcn_mfma_f32_16x16x32_bf16(alo, bhi, acc, 0, 0, 0);
        acc = __builtin_amdgcn_mfma_f32_16x16x32_bf16(ahi, blo, acc, 0, 0, 0);

        float2 o2 = ot_l[t * 16 + lc];   // {off, thr} — same col for all 4 rows
        float* po = out + rowbase + t * 16;
#pragma unroll
        for (int j = 0; j < 4; ++j) {
            float x = acc[j];
            float y = (fabsf(x) < o2.y) ? o2.x : (x + o2.x);
            po[j * MK] = fminf(fmaxf(y, 0.f), 1.f);
        }
    }
}

extern "C" void kernel_launch(void* const* d_in, const int* in_sizes, int n_in,
                              void* d_out, int out_size, void* d_ws, size_t ws_size,
                              hipStream_t stream)
{
    const float* T     = (const float*)d_in[0];
    const float* alpha = (const float*)d_in[1];
    const float* th    = (const float*)d_in[2];
    const float* amb   = (const float*)d_in[3];
    float* out = (float*)d_out;

    // ws layout: Whi[32768 u16] | Wlo[32768 u16] | ot[1024 float2]  = 139,264 B
    unsigned short* Whi = (unsigned short*)d_ws;
    unsigned short* Wlo = Whi + MK * D_;
    float* ot = (float*)(Wlo + MK * D_);

    prep_kernel<<<MK / 256, 256, 0, stream>>>(alpha, th, amb, Whi, Wlo, ot);
    fern_mfma<<<NB_N * NB_MK, 256, 0, stream>>>(T, Whi, Wlo, ot, out);
}

// Round 6
// 197.961 us; speedup vs baseline: 1.0344x; 1.0344x over previous
//
#include <hip/hip_runtime.h>
#include <math.h>

// Problem constants (fixed by the reference)
#define N_TOT 200000
#define D_    32
#define MK    1024          // M*K = 64*16
#define EPS_ZERO 1e-5f
#define EPS_DIV  1e-29f

// Work decomposition: each WAVE owns COLS mk-columns and streams ROWS-row n-tiles.
#define ROWS  16            // n rows per wave-task (one MFMA tile height)
#define COLS  128           // mk cols per wave = NT tiles of 16
#define NT    8             // 16-col tiles per wave
#define NMKE  (MK / COLS)   // 8 column-slices
#define NTILE (N_TOT / ROWS)// 12500 n-tiles
#define NBLK  4096          // blocks (x4 waves = 16384 waves; 2048 per slice)
#define WQ    ((NBLK * 4) / NMKE)   // 2048 waves per column-slice

typedef __attribute__((ext_vector_type(8))) short short8;
typedef __attribute__((ext_vector_type(4))) float f32x4;

__device__ __forceinline__ unsigned short f2bf(float x) {
    unsigned int u = __float_as_uint(x);
    u += 0x7FFFu + ((u >> 16) & 1u);          // round-to-nearest-even
    return (unsigned short)(u >> 16);
}
__device__ __forceinline__ float bf2f(unsigned short h) {
    return __uint_as_float(((unsigned int)h) << 16);
}

// ---------------------------------------------------------------------------
// Prep: softmax(alpha) folded with affine epilogue, split into bf16 hi/lo.
//   W[mk][d] = softmax(alpha[mk])[d] / (pos-neg+eps)   -> Whi + Wlo (bf16)
//   ot[mk]   = { (-th-neg)/(pos-neg+eps),  EPS_ZERO/(pos-neg+eps) }
// Then B = clip( |acc| < thr ? off : acc + off, 0, 1 ),  acc = T·W
// ---------------------------------------------------------------------------
__global__ __launch_bounds__(256) void prep_kernel(
    const float* __restrict__ alpha, const float* __restrict__ th,
    const float* __restrict__ amb,
    unsigned short* __restrict__ Whi, unsigned short* __restrict__ Wlo,
    float* __restrict__ ot)
{
    int mk = blockIdx.x * 256 + threadIdx.x;
    if (mk >= MK) return;
    float v[D_];
    float mx = -1e30f;
#pragma unroll
    for (int d = 0; d < D_; ++d) { v[d] = alpha[mk * D_ + d]; mx = fmaxf(mx, v[d]); }
    float sum = 0.f;
#pragma unroll
    for (int d = 0; d < D_; ++d) { v[d] = expf(v[d] - mx); sum += v[d]; }
    float pos = amb[mk * 2 + 0];
    float neg = amb[mk * 2 + 1];
    float s  = 1.0f / (pos - neg + EPS_DIV);
    float si = s / sum;
#pragma unroll
    for (int d = 0; d < D_; ++d) {
        float w = v[d] * si;
        unsigned short h = f2bf(w);
        Whi[mk * D_ + d] = h;
        Wlo[mk * D_ + d] = f2bf(w - bf2f(h));
    }
    ot[2 * mk + 0] = (0.0f - th[mk] - neg) * s;
    ot[2 * mk + 1] = EPS_ZERO * s;
}

// ---------------------------------------------------------------------------
// Main: zero-LDS, zero-barrier streaming MFMA kernel.
// Each wave: W fragments for its 128 mk-cols held in 64 VGPRs (hoisted),
// {off,thr} in 16 VGPRs, then grid-stride over 16-row n-tiles:
//   load T rows (f32) -> in-register bf16 hi/lo -> 8x(3 MFMA + epilogue+store).
// 3-MFMA hi/lo split keeps fp32-level accuracy (Tlo*Wlo term dropped).
// ---------------------------------------------------------------------------
__global__ __launch_bounds__(256, 3) void fern_mfma(
    const float* __restrict__ T,
    const unsigned short* __restrict__ Whi, const unsigned short* __restrict__ Wlo,
    const float* __restrict__ ot, float* __restrict__ out)
{
    const int tid     = threadIdx.x;
    const int lane    = tid & 63;
    const int wid     = tid >> 6;
    const int wave_id = blockIdx.x * 4 + wid;
    const int mke     = wave_id & (NMKE - 1);   // which 128-col slice
    const int wq      = wave_id >> 3;           // index among waves of this slice
    const int lc      = lane & 15;              // A row / B col / C col
    const int lk      = lane >> 4;              // k-group (8 contiguous k)
    const int mk0     = mke * COLS;

    // ---- hoist W fragments + epilogue constants for this wave's 128 cols
    short8 wh[NT], wl[NT];
    float2 o2[NT];
#pragma unroll
    for (int t = 0; t < NT; ++t) {
        long c = (long)(mk0 + t * 16 + lc);
        wh[t] = *(const short8*)(Whi + c * D_ + lk * 8);
        wl[t] = *(const short8*)(Wlo + c * D_ + lk * 8);
        o2[t] = *(const float2*)(ot + 2 * c);
    }

    // ---- stream n-tiles
    for (int tile = wq; tile < NTILE; tile += WQ) {
        const int n0 = tile * ROWS;

        // T fragment: row n0+lc, k = lk*8 .. lk*8+7  (32B of f32)
        const float* tp = T + (long)(n0 + lc) * D_ + lk * 8;
        float4 v0 = *(const float4*)tp;
        float4 v1 = *(const float4*)(tp + 4);
        float xs[8] = { v0.x, v0.y, v0.z, v0.w, v1.x, v1.y, v1.z, v1.w };
        short8 ah, al;
#pragma unroll
        for (int j = 0; j < 8; ++j) {
            unsigned short h = f2bf(xs[j]);
            ah[j] = (short)h;
            al[j] = (short)f2bf(xs[j] - bf2f(h));
        }

        // C/D layout: col = lane&15, row = (lane>>4)*4 + j  [measured m89/m91]
        // Hoist the 4 output row pointers; t-loop uses imm offsets (t*64 B).
        float* r0 = out + ((long)(n0 + lk * 4 + 0)) * MK + mk0 + lc;
        float* r1 = r0 + MK;
        float* r2 = r1 + MK;
        float* r3 = r2 + MK;

#pragma unroll
        for (int t = 0; t < NT; ++t) {
            f32x4 acc = { 0.f, 0.f, 0.f, 0.f };
            acc = __builtin_amdgcn_mfma_f32_16x16x32_bf16(ah, wh[t], acc, 0, 0, 0);
            acc = __builtin_amdgcn_mfma_f32_16x16x32_bf16(al, wh[t], acc, 0, 0, 0);
            acc = __builtin_amdgcn_mfma_f32_16x16x32_bf16(ah, wl[t], acc, 0, 0, 0);

            const float off = o2[t].x, thr = o2[t].y;
            float x0 = acc[0], x1 = acc[1], x2 = acc[2], x3 = acc[3];
            x0 = (fabsf(x0) < thr) ? off : (x0 + off);
            x1 = (fabsf(x1) < thr) ? off : (x1 + off);
            x2 = (fabsf(x2) < thr) ? off : (x2 + off);
            x3 = (fabsf(x3) < thr) ? off : (x3 + off);
            r0[t * 16] = fminf(fmaxf(x0, 0.f), 1.f);
            r1[t * 16] = fminf(fmaxf(x1, 0.f), 1.f);
            r2[t * 16] = fminf(fmaxf(x2, 0.f), 1.f);
            r3[t * 16] = fminf(fmaxf(x3, 0.f), 1.f);
        }
    }
}

extern "C" void kernel_launch(void* const* d_in, const int* in_sizes, int n_in,
                              void* d_out, int out_size, void* d_ws, size_t ws_size,
                              hipStream_t stream)
{
    const float* T     = (const float*)d_in[0];
    const float* alpha = (const float*)d_in[1];
    const float* th    = (const float*)d_in[2];
    const float* amb   = (const float*)d_in[3];
    float* out = (float*)d_out;

    // ws layout: Whi[32768 u16] | Wlo[32768 u16] | ot[1024 float2]  = 139,264 B
    unsigned short* Whi = (unsigned short*)d_ws;
    unsigned short* Wlo = Whi + MK * D_;
    float* ot = (float*)(Wlo + MK * D_);

    prep_kernel<<<MK / 256, 256, 0, stream>>>(alpha, th, amb, Whi, Wlo, ot);
    fern_mfma<<<NBLK, 256, 0, stream>>>(T, Whi, Wlo, ot, out);
}